// Round 18
// baseline (364.645 us; speedup 1.0000x reference)
//
#include <hip/hip_runtime.h>
#include <hip/hip_bf16.h>
#include <math.h>

// ---------------------------------------------------------------------------
// CollaborativeExpertsWrapper — round 18: extend the confirmed NT-streaming
// mechanism (R17: o-read NT -> 382.4 -> 358.7 us) to prep_k's read-once
// inputs (rgb/audio f32, W f32), keeping prep's OUTPUTS (xrb, wt) resident
// in L3 for qkv's 4x re-reads.
//   1 prep_k (NT in) ; 2 qkv_mean_k (NT o) ; 3 finalize_mean_k ; 4 gemm_f32_k
//   5 attn_pool_k ; 6,7 gemm_f32_2w ; 8 ntg_k ; 9 final_k
// ---------------------------------------------------------------------------

using bf16x8 = __attribute__((ext_vector_type(8))) __bf16;
using f32x4  = __attribute__((ext_vector_type(4))) float;

// ---- workspace byte offsets ------------------------------------------------
enum : size_t {
  B_PART = 0,                                    // [128][16][2][512] f32 = 8 MB
  B_OM   = B_PART + (size_t)128*16*2*512*4,
  B_OO   = B_OM   + (size_t)128*512*4,           // 128*1024 f32 (raw)
  B_G    = B_OO   + (size_t)128*1024*4,          // 128*128 f32
  B_PP   = B_G    + (size_t)128*128*4,           // [2][128][512] f32
  B_PO   = B_PP   + (size_t)2*128*512*4,
  B_FEAT = B_PO   + (size_t)2*128*512*4,
  B_QBF  = B_FEAT + (size_t)2*128*512*4,         // [2][8192][512] bf16
  B_KBF  = B_QBF  + (size_t)2*8192*512*2,
  B_VBF  = B_KBF  + (size_t)2*8192*512*2,
  B_XR   = B_VBF  + (size_t)2*8192*512*2,
  B_XA   = B_XR   + (size_t)8192*2048*2,
  B_WT   = B_XA   + (size_t)8192*128*2,
  B_END  = B_WT   + (size_t)3*512*2048*2 + (size_t)3*512*128*2
};

__device__ __forceinline__ unsigned short f2bf(float f) {
  __hip_bfloat16 h = __float2bfloat16(f);
  return __builtin_bit_cast(unsigned short, h);
}
__device__ __forceinline__ unsigned pack2(float a, float b) {
  return (unsigned)f2bf(a) | ((unsigned)f2bf(b) << 16);
}

// ---- 1: prep (casts only; NT loads on read-once inputs) --------------------
struct PrepArgs {
  const float* xr; unsigned short* xrb;
  const float* xa; unsigned short* xab;
  const float* w[6];
  unsigned short* wt[6];
};

__device__ __forceinline__ void castT64(const float* __restrict__ W,
                                        unsigned short* __restrict__ Wt,
                                        int K, int n0, int k0, int tid) {
  __shared__ float t[64][65];
  int c = tid & 63, r4 = tid >> 6;
#pragma unroll
  for (int i = 0; i < 16; ++i) {
    int r = r4 * 16 + i;
    t[c][r] = __builtin_nontemporal_load(&W[(size_t)(k0 + r) * 512 + n0 + c]);
  }
  __syncthreads();
  int nr = tid >> 3, kk = (tid & 7) * 8;
#pragma unroll
  for (int p = 0; p < 2; ++p) {
    int n = nr + p * 32;
    float4 x0 = *(const float4*)&t[n][kk];
    float4 x1 = *(const float4*)&t[n][kk + 4];
    uint4 pk;
    pk.x = pack2(x0.x, x0.y); pk.y = pack2(x0.z, x0.w);
    pk.z = pack2(x1.x, x1.y); pk.w = pack2(x1.z, x1.w);
    *(uint4*)&Wt[(size_t)(n0 + n) * K + k0 + kk] = pk;
  }
}

__device__ __forceinline__ void cast8(const float* __restrict__ x,
                                      unsigned short* __restrict__ y,
                                      int i, int stride, int total) {
  const f32x4* xv = (const f32x4*)x;
  for (; i < total; i += stride) {
    f32x4 v0 = __builtin_nontemporal_load(xv + (size_t)i * 2);
    f32x4 v1 = __builtin_nontemporal_load(xv + (size_t)i * 2 + 1);
    uint4 pk;
    pk.x = pack2(v0.x, v0.y); pk.y = pack2(v0.z, v0.w);
    pk.z = pack2(v1.x, v1.y); pk.w = pack2(v1.z, v1.w);
    *(uint4*)(y + (size_t)i * 8) = pk;
  }
}

__global__ __launch_bounds__(256) void prep_k(PrepArgs a) {
  int bid = blockIdx.x, tid = threadIdx.x;
  if (bid < 768) {
    int w = bid >> 8, t = bid & 255;
    castT64(a.w[w], a.wt[w], 2048, (t >> 5) * 64, (t & 31) * 64, tid);
  } else if (bid < 816) {
    int t = bid - 768; int w = t >> 4; t &= 15;
    castT64(a.w[3 + w], a.wt[3 + w], 128, (t >> 1) * 64, (t & 1) * 64, tid);
  } else if (bid < 1840) {
    cast8(a.xr, a.xrb, (bid - 816) * 256 + tid, 262144, 2097152);
  } else {
    cast8(a.xa, a.xab, (bid - 1840) * 256 + tid, 16384, 131072);
  }
}

// ---- 2: qkv (bf16 MFMA, 2-phase dbuf, swizzled LDS) + o-mean (NT loads) ----
struct QkvAll {
  const unsigned short* A[2];
  const unsigned short* Wt[6];
  const float* bias[6];
  unsigned short* out[6];
  const float* o; float* part;
};

__device__ __forceinline__ void stage16(const void* g, void* l) {
  __builtin_amdgcn_global_load_lds((const __attribute__((address_space(1))) void*)g,
                                   (__attribute__((address_space(3))) void*)l, 16, 0, 0);
}

__global__ __launch_bounds__(256) void qkv_mean_k(QkvAll args) {
  __shared__ __align__(16) char smem[32768];

  int id = blockIdx.x;
  int blk = id / 448, off = id % 448;

  if (off >= 192) {                     // ---- mean partial block (NT path) ----
    int mb = blk * 256 + (off - 192);   // 0..2047
    int c = mb & 15, b = mb >> 4;
    const f32x4* base = (const f32x4*)(args.o + ((size_t)b * 1024 + (size_t)c * 64) * 512);
    int tid = threadIdx.x;
    int d4 = tid & 127, half = tid >> 7;
    f32x4 s = {0.f, 0.f, 0.f, 0.f};
    for (int t = half; t < 64; t += 2) {
      f32x4 v = __builtin_nontemporal_load(base + (size_t)t * 128 + d4);
      s += v;
    }
    f32x4* dst = (f32x4*)(args.part + (((size_t)b * 16 + c) * 2 + half) * 512) + d4;
    __builtin_nontemporal_store(s, dst);
    return;
  }

  int qid = blk * 192 + off;            // 0..1535
  int mi = qid >= 768 ? 1 : 0; qid -= mi * 768;
  int by = qid & 63, bx = (qid >> 6) & 3, bz = qid >> 8;   // XCD-affine
  int K = mi ? 128 : 2048;
  int nt = K >> 5;
  const unsigned short* A = args.A[mi];
  int wi = mi * 3 + bz;
  const unsigned short* Bt = args.Wt[wi];
  const float* bias = args.bias[wi];

  int tid = threadIdx.x;
  int l = tid & 63, w = tid >> 6;
  int row0 = by * 128, col0 = bx * 128;
  int wrow = (w & 1) * 64, wcol = (w >> 1) * 64;
  int kg = l >> 4, lr = l & 15;

  float bv[4];
#pragma unroll
  for (int n = 0; n < 4; ++n) bv[n] = bias[col0 + wcol + n * 16 + lr];
  asm volatile("" :: "v"(bv[0]), "v"(bv[1]), "v"(bv[2]), "v"(bv[3]));

  auto stage_pair = [&](char* dbuf, int k0s) {
#pragma unroll
    for (int i = 0; i < 2; ++i) {
      int c = w * 128 + i * 64 + l;
      int B_ = c << 4;
      int e6 = ((B_ >> 6) ^ (B_ >> 8)) & 1;
      int E  = B_ ^ (e6 << 4) ^ (((B_ >> 7) & 1) << 5) ^ (((B_ >> 8) & 1) << 6);
      int r = E >> 6, s = ((E >> 4) & 3) << 3;
      stage16(A + (size_t)(row0 + r) * K + k0s + s, dbuf + (w * 128 + i * 64) * 16);
      stage16(Bt + (size_t)(col0 + r) * K + k0s + s, dbuf + 8192 + (w * 128 + i * 64) * 16);
    }
  };

  f32x4 acc[4][4] = {};
  int xorA = (lr & 7) << 4;

  stage_pair(smem, 0);
  int cur = 0;
  for (int t = 0; t < nt; ++t) {
    if (t + 1 < nt) {
      stage_pair(smem + ((cur ^ 1) << 14), (t + 1) << 5);
      asm volatile("s_waitcnt vmcnt(4)" ::: "memory");
    } else {
      asm volatile("s_waitcnt vmcnt(0)" ::: "memory");
    }
    __builtin_amdgcn_s_barrier();
    __builtin_amdgcn_sched_barrier(0);

    const char* Ab = smem + (cur << 14);
    const char* Bb = Ab + 8192;
    bf16x8 af[4], bfr[4];
#pragma unroll
    for (int m = 0; m < 4; ++m) {
      int ra = wrow + m * 16 + lr;
      int rb = wcol + m * 16 + lr;
      af[m]  = *(const bf16x8*)(Ab + (((ra << 6) + (kg << 4)) ^ xorA));
      bfr[m] = *(const bf16x8*)(Bb + (((rb << 6) + (kg << 4)) ^ xorA));
    }
#pragma unroll
    for (int m = 0; m < 4; ++m)
#pragma unroll
      for (int n = 0; n < 4; ++n)
        acc[m][n] = __builtin_amdgcn_mfma_f32_16x16x32_bf16(af[m], bfr[n], acc[m][n], 0, 0, 0);

    __builtin_amdgcn_sched_barrier(0);
    __builtin_amdgcn_s_barrier();
    cur ^= 1;
  }

  float* cst = (float*)(smem) + w * 1024;
  unsigned short* C = args.out[wi];
  int rr = l >> 3, q = l & 7;
#pragma unroll
  for (int m = 0; m < 4; ++m) {
#pragma unroll
    for (int n = 0; n < 4; ++n) {
      int g0 = (n * 16 + lr) >> 3, o0 = lr & 7;
#pragma unroll
      for (int j = 0; j < 4; ++j) {
        int row = kg * 4 + j;
        cst[row * 64 + (((g0 ^ (row & 7)) << 3) | o0)] = acc[m][n][j] + bv[n];
      }
    }
#pragma unroll
    for (int p = 0; p < 2; ++p) {
      int row = rr + p * 8;
      int grp = q ^ (row & 7);
      float4 x0 = *(const float4*)&cst[row * 64 + grp * 8];
      float4 x1 = *(const float4*)&cst[row * 64 + grp * 8 + 4];
      uint4 pk;
      pk.x = pack2(x0.x, x0.y); pk.y = pack2(x0.z, x0.w);
      pk.z = pack2(x1.x, x1.y); pk.w = pack2(x1.z, x1.w);
      *(uint4*)&C[(size_t)(row0 + wrow + m * 16 + row) * 512 + col0 + wcol + q * 8] = pk;
    }
  }
}

// ---- 3: finalize mean ------------------------------------------------------
__global__ __launch_bounds__(512) void finalize_mean_k(const float* __restrict__ part,
                                                       float* __restrict__ om) {
  int b = blockIdx.x, d = threadIdx.x;
  float s = 0.f;
  for (int c = 0; c < 32; ++c) s += part[((size_t)b * 32 + c) * 512 + d];
  om[(size_t)b * 512 + d] = s * (1.f / 1024.f);
}

// ---- 4: f32 GEMM (expand only) ---------------------------------------------
__global__ __launch_bounds__(256) void gemm_f32_k(
    const float* __restrict__ A, int lda,
    const float* __restrict__ W, int ldw,
    const float* __restrict__ bias,
    float* __restrict__ C, int ldc, int K) {
  __shared__ float As[16][65];
  __shared__ float Ws[16][64];
  int tid = threadIdx.x;
  int tx = tid & 15, ty = tid >> 4;
  int row0 = blockIdx.y * 64, col0 = blockIdx.x * 64;
  float acc[4][4] = {};
  int ar = tid >> 2, ac = (tid & 3) << 2;
  int wr = tid >> 4, wc = (tid & 15) << 2;
  for (int k0 = 0; k0 < K; k0 += 16) {
    float4 av = *(const float4*)(A + (size_t)(row0 + ar) * lda + k0 + ac);
    As[ac + 0][ar] = av.x; As[ac + 1][ar] = av.y;
    As[ac + 2][ar] = av.z; As[ac + 3][ar] = av.w;
    float4 wv = *(const float4*)(W + (size_t)(k0 + wr) * ldw + col0 + wc);
    *(float4*)&Ws[wr][wc] = wv;
    __syncthreads();
#pragma unroll
    for (int k = 0; k < 16; ++k) {
      float a0 = As[k][(ty << 2) + 0], a1 = As[k][(ty << 2) + 1];
      float a2 = As[k][(ty << 2) + 2], a3 = As[k][(ty << 2) + 3];
      float4 w = *(const float4*)&Ws[k][tx << 2];
      acc[0][0] += a0 * w.x; acc[0][1] += a0 * w.y; acc[0][2] += a0 * w.z; acc[0][3] += a0 * w.w;
      acc[1][0] += a1 * w.x; acc[1][1] += a1 * w.y; acc[1][2] += a1 * w.z; acc[1][3] += a1 * w.w;
      acc[2][0] += a2 * w.x; acc[2][1] += a2 * w.y; acc[2][2] += a2 * w.z; acc[2][3] += a2 * w.w;
      acc[3][0] += a3 * w.x; acc[3][1] += a3 * w.y; acc[3][2] += a3 * w.z; acc[3][3] += a3 * w.w;
    }
    __syncthreads();
  }
  float4 bv = *(const float4*)(bias + col0 + (tx << 2));
#pragma unroll
  for (int i = 0; i < 4; ++i) {
    float4 ov;
    ov.x = acc[i][0] + bv.x; ov.y = acc[i][1] + bv.y;
    ov.z = acc[i][2] + bv.z; ov.w = acc[i][3] + bv.w;
    *(float4*)(C + (size_t)(row0 + (ty << 2) + i) * ldc + col0 + (tx << 2)) = ov;
  }
}

// ---- dual-weight f32 GEMM ---------------------------------------------------
__global__ __launch_bounds__(256) void gemm_f32_2w_k(
    const float* __restrict__ A,
    const float* __restrict__ W0, const float* __restrict__ W1,
    const float* __restrict__ b0, const float* __restrict__ b1,
    float* __restrict__ C) {
  const float* W = (blockIdx.y >= 2) ? W1 : W0;
  const float* bias = (blockIdx.y >= 2) ? b1 : b0;
  __shared__ float As[16][65];
  __shared__ float Ws[16][64];
  int tid = threadIdx.x;
  int tx = tid & 15, ty = tid >> 4;
  int row0 = blockIdx.y * 64, col0 = blockIdx.x * 64;
  float acc[4][4] = {};
  int ar = tid >> 2, ac = (tid & 3) << 2;
  int wr = tid >> 4, wc = (tid & 15) << 2;
  for (int k0 = 0; k0 < 512; k0 += 16) {
    float4 av = *(const float4*)(A + (size_t)(row0 + ar) * 512 + k0 + ac);
    As[ac + 0][ar] = av.x; As[ac + 1][ar] = av.y;
    As[ac + 2][ar] = av.z; As[ac + 3][ar] = av.w;
    float4 wv = *(const float4*)(W + (size_t)(k0 + wr) * 512 + col0 + wc);
    *(float4*)&Ws[wr][wc] = wv;
    __syncthreads();
#pragma unroll
    for (int k = 0; k < 16; ++k) {
      float a0 = As[k][(ty << 2) + 0], a1 = As[k][(ty << 2) + 1];
      float a2 = As[k][(ty << 2) + 2], a3 = As[k][(ty << 2) + 3];
      float4 w = *(const float4*)&Ws[k][tx << 2];
      acc[0][0] += a0 * w.x; acc[0][1] += a0 * w.y; acc[0][2] += a0 * w.z; acc[0][3] += a0 * w.w;
      acc[1][0] += a1 * w.x; acc[1][1] += a1 * w.y; acc[1][2] += a1 * w.z; acc[1][3] += a1 * w.w;
      acc[2][0] += a2 * w.x; acc[2][1] += a2 * w.y; acc[2][2] += a2 * w.z; acc[2][3] += a2 * w.w;
      acc[3][0] += a3 * w.x; acc[3][1] += a3 * w.y; acc[3][2] += a3 * w.z; acc[3][3] += a3 * w.w;
    }
    __syncthreads();
  }
  float4 bv = *(const float4*)(bias + col0 + (tx << 2));
#pragma unroll
  for (int i = 0; i < 4; ++i) {
    float4 ov;
    ov.x = acc[i][0] + bv.x; ov.y = acc[i][1] + bv.y;
    ov.z = acc[i][2] + bv.z; ov.w = acc[i][3] + bv.w;
    *(float4*)(C + (size_t)(row0 + (ty << 2) + i) * 512 + col0 + (tx << 2)) = ov;
  }
}

// ---- 5: attention pool; block=(b,m), wave=head; bf16 V ---------------------
__global__ __launch_bounds__(256) void attn_pool_k(
    const unsigned short* __restrict__ qbf,
    const unsigned short* __restrict__ kbf,
    const unsigned short* __restrict__ vbf,
    float* __restrict__ pooled) {
  __shared__ float wlds[4][64];
  int b = blockIdx.x, m = blockIdx.y;
  int tid = threadIdx.x;
  int w = tid >> 6, l = tid & 63, lr = l & 15, g = l >> 4;
  size_t base = ((size_t)m * 8192 + (size_t)b * 64) * 512 + w * 128;  // head = w

  bf16x8 qf[4][4];
#pragma unroll
  for (int tb = 0; tb < 4; ++tb)
#pragma unroll
    for (int ks = 0; ks < 4; ++ks)
      qf[tb][ks] = *(const bf16x8*)(qbf + base + (size_t)(tb * 16 + lr) * 512 + ks * 32 + g * 8);

  f32x4 acc[4][4] = {};
#pragma unroll
  for (int sb = 0; sb < 4; ++sb) {
    bf16x8 kf[4];
#pragma unroll
    for (int ks = 0; ks < 4; ++ks)
      kf[ks] = *(const bf16x8*)(kbf + base + (size_t)(sb * 16 + lr) * 512 + ks * 32 + g * 8);
#pragma unroll
    for (int tb = 0; tb < 4; ++tb)
#pragma unroll
      for (int ks = 0; ks < 4; ++ks)
        acc[sb][tb] = __builtin_amdgcn_mfma_f32_16x16x32_bf16(kf[ks], qf[tb][ks], acc[sb][tb], 0, 0, 0);
  }

  const float scale = 0.08838834764831845f;
  float mx[4] = {-INFINITY, -INFINITY, -INFINITY, -INFINITY};
#pragma unroll
  for (int sb = 0; sb < 4; ++sb)
#pragma unroll
    for (int tb = 0; tb < 4; ++tb)
#pragma unroll
      for (int j = 0; j < 4; ++j) {
        acc[sb][tb][j] *= scale;
        mx[tb] = fmaxf(mx[tb], acc[sb][tb][j]);
      }
#pragma unroll
  for (int tb = 0; tb < 4; ++tb) {
    mx[tb] = fmaxf(mx[tb], __shfl_xor(mx[tb], 16));
    mx[tb] = fmaxf(mx[tb], __shfl_xor(mx[tb], 32));
  }
  float sm[4] = {0.f, 0.f, 0.f, 0.f};
#pragma unroll
  for (int sb = 0; sb < 4; ++sb)
#pragma unroll
    for (int tb = 0; tb < 4; ++tb)
#pragma unroll
      for (int j = 0; j < 4; ++j) {
        float e = expf(acc[sb][tb][j] - mx[tb]);
        acc[sb][tb][j] = e;
        sm[tb] += e;
      }
  float inv[4];
#pragma unroll
  for (int tb = 0; tb < 4; ++tb) {
    sm[tb] += __shfl_xor(sm[tb], 16);
    sm[tb] += __shfl_xor(sm[tb], 32);
    inv[tb] = 1.f / sm[tb];
  }
#pragma unroll
  for (int sb = 0; sb < 4; ++sb)
#pragma unroll
    for (int j = 0; j < 4; ++j) {
      float cs = acc[sb][0][j] * inv[0] + acc[sb][1][j] * inv[1]
               + acc[sb][2][j] * inv[2] + acc[sb][3][j] * inv[3];
      cs += __shfl_xor(cs, 1);
      cs += __shfl_xor(cs, 2);
      cs += __shfl_xor(cs, 4);
      cs += __shfl_xor(cs, 8);
      if (lr == 0) wlds[w][sb * 16 + g * 4 + j] = cs * (1.f / 64.f);
    }
  __syncthreads();

  int h = tid >> 6, c2 = (tid & 63) << 1;
  size_t vbase = ((size_t)m * 8192 + (size_t)b * 64) * 512 + h * 128 + c2;
  float s0 = 0.f, s1 = 0.f;
#pragma unroll 8
  for (int s = 0; s < 64; ++s) {
    unsigned u = *(const unsigned*)(vbf + vbase + (size_t)s * 512);
    float vlo = __builtin_bit_cast(float, u << 16);
    float vhi = __builtin_bit_cast(float, u & 0xffff0000u);
    float wv = wlds[h][s];
    s0 += wv * vlo; s1 += wv * vhi;
  }
  float2 o2 = {s0, s1};
  *(float2*)(pooled + ((size_t)m * 128 + b) * 512 + h * 128 + c2) = o2;
}

// ---- 8: G = normalize_rows(oo_raw) @ feat^T --------------------------------
__global__ __launch_bounds__(256) void ntg_k(const float* __restrict__ oo,
                                             const float* __restrict__ feat,
                                             float* __restrict__ G) {
  __shared__ float As[16][33], Bs[16][33];
  __shared__ float inv32[32];
  int tid = threadIdx.x;
  int row0 = blockIdx.y * 32, col0 = blockIdx.x * 32;
  int ar = tid >> 3, aq = tid & 7;
  int ty = tid >> 4, tx = tid & 15;
  float acc[2][2] = {};
  float ssq = 0.f;
  for (int k0 = 0; k0 < 1024; k0 += 16) {
    float2 av = *(const float2*)(oo + (size_t)(row0 + ar) * 1024 + k0 + aq * 2);
    As[aq * 2 + 0][ar] = av.x;
    As[aq * 2 + 1][ar] = av.y;
    ssq += av.x * av.x + av.y * av.y;
    int kk = k0 + aq * 2;
    float2 bv = *(const float2*)(feat + (size_t)((kk >> 9) * 128 + col0 + ar) * 512 + (kk & 511));
    Bs[aq * 2 + 0][ar] = bv.x;
    Bs[aq * 2 + 1][ar] = bv.y;
    __syncthreads();
#pragma unroll
    for (int k = 0; k < 16; ++k) {
      float a0 = As[k][ty * 2], a1 = As[k][ty * 2 + 1];
      float b0 = Bs[k][tx * 2], b1 = Bs[k][tx * 2 + 1];
      acc[0][0] += a0 * b0; acc[0][1] += a0 * b1;
      acc[1][0] += a1 * b0; acc[1][1] += a1 * b1;
    }
    __syncthreads();
  }
  ssq += __shfl_xor(ssq, 1);
  ssq += __shfl_xor(ssq, 2);
  ssq += __shfl_xor(ssq, 4);
  if (aq == 0) inv32[ar] = 1.f / fmaxf(sqrtf(ssq), 1e-12f);
  __syncthreads();
#pragma unroll
  for (int i = 0; i < 2; ++i)
#pragma unroll
    for (int j = 0; j < 2; ++j)
      G[(size_t)(row0 + ty * 2 + i) * 128 + col0 + tx * 2 + j] = acc[i][j] * inv32[ty * 2 + i];
}

// ---- 9: final loss/acc ------------------------------------------------------
__global__ __launch_bounds__(128) void final_k(const float* __restrict__ G,
                                               const int* __restrict__ gmask,
                                               float* __restrict__ out) {
  __shared__ float cm[2][128], vd[2][128], tp[2][128], cv[2][128];
  __shared__ int gm[128];
  int b = threadIdx.x;
  gm[b] = gmask[b];
  __syncthreads();
  for (int r = 0; r < 2; ++r) {
    bool gb = gm[b] != 0;
    float s0 = G[b * 128 + b];
    int cnt = 0;
    float lsum = 0.f, selsum = 0.f, smax = -INFINITY;
    bool anym = false;
    for (int i = 0; i < 128; ++i) {
      int j = (b - i + 128) & 127;
      bool mk = gb && (gm[j] != 0);
      float sv = (r == 0) ? G[b * 128 + j] : G[j * 128 + b];
      if (mk) {
        selsum += sv; anym = true;
        smax = fmaxf(smax, sv);
        if (i >= 1) { cnt++; lsum += fmaxf(0.f, 1.f + sv - s0); }
      }
    }
    cm[r][b] = (cnt > 0) ? (lsum / (float)cnt) : 0.f;
    vd[r][b] = (cnt > 0) ? 1.f : 0.f;
    bool colvalid = (selsum != 0.f) && anym;
    tp[r][b] = (colvalid && (s0 >= smax)) ? 1.f : 0.f;
    cv[r][b] = colvalid ? 1.f : 0.f;
  }
  __syncthreads();
  if (b == 0) {
    float loss = 0.f, acc = 0.f;
    for (int r = 0; r < 2; ++r) {
      float scm = 0, svd = 0, stp = 0, scv = 0;
      for (int i = 0; i < 128; ++i) { scm += cm[r][i]; svd += vd[r][i]; stp += tp[r][i]; scv += cv[r][i]; }
      loss += scm / fmaxf(svd, 1.f);
      acc += stp / fmaxf(scv, 1.f);
    }
    out[0] = loss;
    out[1] = acc * 0.5f;
  }
}

extern "C" void kernel_launch(void* const* d_in, const int* in_sizes, int n_in,
                              void* d_out, int out_size, void* d_ws, size_t ws_size,
                              hipStream_t stream) {
  const float* o     = (const float*)d_in[0];
  const float* rgb   = (const float*)d_in[1];
  const float* audio = (const float*)d_in[2];
  const int* gmask   = (const int*)d_in[3];
  const float* W[2][10];
  for (int m = 0; m < 2; ++m)
    for (int w = 0; w < 10; ++w) W[m][w] = (const float*)d_in[4 + m * 10 + w];
  const float* expand_W = (const float*)d_in[24];
  const float* expand_b = (const float*)d_in[25];

  char* ws = (char*)d_ws;
  float* part = (float*)(ws + B_PART);
  float* om   = (float*)(ws + B_OM);
  float* oo   = (float*)(ws + B_OO);
  float* G    = (float*)(ws + B_G);
  float* pp2  = (float*)(ws + B_PP);
  float* po2  = (float*)(ws + B_PO);
  float* feat2= (float*)(ws + B_FEAT);
  unsigned short* qbf = (unsigned short*)(ws + B_QBF);
  unsigned short* kbf = (unsigned short*)(ws + B_KBF);
  unsigned short* vbf = (unsigned short*)(ws + B_VBF);
  unsigned short* xrb = (unsigned short*)(ws + B_XR);
  unsigned short* xab = (unsigned short*)(ws + B_XA);
  unsigned short* wt  = (unsigned short*)(ws + B_WT);
  unsigned short* wtp[6];
  wtp[0] = wt;
  wtp[1] = wtp[0] + (size_t)512 * 2048;
  wtp[2] = wtp[1] + (size_t)512 * 2048;
  wtp[3] = wtp[2] + (size_t)512 * 2048;
  wtp[4] = wtp[3] + (size_t)512 * 128;
  wtp[5] = wtp[4] + (size_t)512 * 128;

  // 1: prep (casts only; NT input loads)
  PrepArgs pa;
  pa.xr = rgb;   pa.xrb = xrb;
  pa.xa = audio; pa.xab = xab;
  pa.w[0] = W[0][0]; pa.w[1] = W[0][2]; pa.w[2] = W[0][4];
  pa.w[3] = W[1][0]; pa.w[4] = W[1][2]; pa.w[5] = W[1][4];
  for (int i = 0; i < 6; ++i) pa.wt[i] = wtp[i];
  prep_k<<<1904, 256, 0, stream>>>(pa);

  // 2: qkv + interleaved mean partials (NT o-read)
  QkvAll qa;
  qa.A[0] = xrb; qa.A[1] = xab;
  for (int i = 0; i < 6; ++i) qa.Wt[i] = wtp[i];
  qa.bias[0] = W[0][1]; qa.bias[1] = W[0][3]; qa.bias[2] = W[0][5];
  qa.bias[3] = W[1][1]; qa.bias[4] = W[1][3]; qa.bias[5] = W[1][5];
  qa.out[0] = qbf;                       qa.out[1] = kbf;                       qa.out[2] = vbf;
  qa.out[3] = qbf + (size_t)8192 * 512;  qa.out[4] = kbf + (size_t)8192 * 512;  qa.out[5] = vbf + (size_t)8192 * 512;
  qa.o = o; qa.part = part;
  qkv_mean_k<<<3584, 256, 0, stream>>>(qa);

  // 3-4: oo branch
  finalize_mean_k<<<128, 512, 0, stream>>>(part, om);
  gemm_f32_k<<<dim3(16, 2), 256, 0, stream>>>(om, 512, expand_W, 1024, expand_b, oo, 1024, 512);

  // 5: attention pools
  attn_pool_k<<<dim3(128, 2), 256, 0, stream>>>(qbf, kbf, vbf, pp2);

  // 6-7: po = pp @ Wo + bo ; feat = po @ W2 + b2
  gemm_f32_2w_k<<<dim3(8, 4), 256, 0, stream>>>(pp2, W[0][6], W[1][6], W[0][7], W[1][7], po2);
  gemm_f32_2w_k<<<dim3(8, 4), 256, 0, stream>>>(po2, W[0][8], W[1][8], W[0][9], W[1][9], feat2);

  // 8-9: ranking
  ntg_k<<<dim3(4, 4), 256, 0, stream>>>(oo, feat2, G);
  final_k<<<1, 128, 0, stream>>>(G, gmask, (float*)d_out);
}

// Round 19
// 358.352 us; speedup vs baseline: 1.0176x; 1.0176x over previous
//
#include <hip/hip_runtime.h>
#include <hip/hip_bf16.h>
#include <math.h>

// ---------------------------------------------------------------------------
// CollaborativeExpertsWrapper — round 19: FINAL — revert to R17 verbatim
// (best measured: 358.7 us). NT streaming only on the o-read/part-store,
// which runs CONCURRENTLY with qkv (the confirmed mechanism); R18's prep-NT
// extension was null-to-negative and is dropped.
//   1 prep_k ; 2 qkv_mean_k (NT o) ; 3 finalize_mean_k ; 4 gemm_f32_k
//   5 attn_pool_k ; 6,7 gemm_f32_2w ; 8 ntg_k ; 9 final_k
// ---------------------------------------------------------------------------

using bf16x8 = __attribute__((ext_vector_type(8))) __bf16;
using f32x4  = __attribute__((ext_vector_type(4))) float;

// ---- workspace byte offsets ------------------------------------------------
enum : size_t {
  B_PART = 0,                                    // [128][16][2][512] f32 = 8 MB
  B_OM   = B_PART + (size_t)128*16*2*512*4,
  B_OO   = B_OM   + (size_t)128*512*4,           // 128*1024 f32 (raw)
  B_G    = B_OO   + (size_t)128*1024*4,          // 128*128 f32
  B_PP   = B_G    + (size_t)128*128*4,           // [2][128][512] f32
  B_PO   = B_PP   + (size_t)2*128*512*4,
  B_FEAT = B_PO   + (size_t)2*128*512*4,
  B_QBF  = B_FEAT + (size_t)2*128*512*4,         // [2][8192][512] bf16
  B_KBF  = B_QBF  + (size_t)2*8192*512*2,
  B_VBF  = B_KBF  + (size_t)2*8192*512*2,
  B_XR   = B_VBF  + (size_t)2*8192*512*2,
  B_XA   = B_XR   + (size_t)8192*2048*2,
  B_WT   = B_XA   + (size_t)8192*128*2,
  B_END  = B_WT   + (size_t)3*512*2048*2 + (size_t)3*512*128*2
};

__device__ __forceinline__ unsigned short f2bf(float f) {
  __hip_bfloat16 h = __float2bfloat16(f);
  return __builtin_bit_cast(unsigned short, h);
}
__device__ __forceinline__ unsigned pack2(float a, float b) {
  return (unsigned)f2bf(a) | ((unsigned)f2bf(b) << 16);
}

// ---- 1: prep (casts only) --------------------------------------------------
struct PrepArgs {
  const float* xr; unsigned short* xrb;
  const float* xa; unsigned short* xab;
  const float* w[6];
  unsigned short* wt[6];
};

__device__ __forceinline__ void castT64(const float* __restrict__ W,
                                        unsigned short* __restrict__ Wt,
                                        int K, int n0, int k0, int tid) {
  __shared__ float t[64][65];
  int c = tid & 63, r4 = tid >> 6;
#pragma unroll
  for (int i = 0; i < 16; ++i) {
    int r = r4 * 16 + i;
    t[c][r] = W[(size_t)(k0 + r) * 512 + n0 + c];
  }
  __syncthreads();
  int nr = tid >> 3, kk = (tid & 7) * 8;
#pragma unroll
  for (int p = 0; p < 2; ++p) {
    int n = nr + p * 32;
    float4 x0 = *(const float4*)&t[n][kk];
    float4 x1 = *(const float4*)&t[n][kk + 4];
    uint4 pk;
    pk.x = pack2(x0.x, x0.y); pk.y = pack2(x0.z, x0.w);
    pk.z = pack2(x1.x, x1.y); pk.w = pack2(x1.z, x1.w);
    *(uint4*)&Wt[(size_t)(n0 + n) * K + k0 + kk] = pk;
  }
}

__device__ __forceinline__ void cast8(const float* __restrict__ x,
                                      unsigned short* __restrict__ y,
                                      int i, int stride, int total) {
  for (; i < total; i += stride) {
    float4 v0 = *(const float4*)(x + (size_t)i * 8);
    float4 v1 = *(const float4*)(x + (size_t)i * 8 + 4);
    uint4 pk;
    pk.x = pack2(v0.x, v0.y); pk.y = pack2(v0.z, v0.w);
    pk.z = pack2(v1.x, v1.y); pk.w = pack2(v1.z, v1.w);
    *(uint4*)(y + (size_t)i * 8) = pk;
  }
}

__global__ __launch_bounds__(256) void prep_k(PrepArgs a) {
  int bid = blockIdx.x, tid = threadIdx.x;
  if (bid < 768) {
    int w = bid >> 8, t = bid & 255;
    castT64(a.w[w], a.wt[w], 2048, (t >> 5) * 64, (t & 31) * 64, tid);
  } else if (bid < 816) {
    int t = bid - 768; int w = t >> 4; t &= 15;
    castT64(a.w[3 + w], a.wt[3 + w], 128, (t >> 1) * 64, (t & 1) * 64, tid);
  } else if (bid < 1840) {
    cast8(a.xr, a.xrb, (bid - 816) * 256 + tid, 262144, 2097152);
  } else {
    cast8(a.xa, a.xab, (bid - 1840) * 256 + tid, 16384, 131072);
  }
}

// ---- 2: qkv (bf16 MFMA, 2-phase dbuf, swizzled LDS) + o-mean (NT loads) ----
struct QkvAll {
  const unsigned short* A[2];
  const unsigned short* Wt[6];
  const float* bias[6];
  unsigned short* out[6];
  const float* o; float* part;
};

__device__ __forceinline__ void stage16(const void* g, void* l) {
  __builtin_amdgcn_global_load_lds((const __attribute__((address_space(1))) void*)g,
                                   (__attribute__((address_space(3))) void*)l, 16, 0, 0);
}

__global__ __launch_bounds__(256) void qkv_mean_k(QkvAll args) {
  __shared__ __align__(16) char smem[32768];

  int id = blockIdx.x;
  int blk = id / 448, off = id % 448;

  if (off >= 192) {                     // ---- mean partial block (NT path) ----
    int mb = blk * 256 + (off - 192);   // 0..2047
    int c = mb & 15, b = mb >> 4;
    const f32x4* base = (const f32x4*)(args.o + ((size_t)b * 1024 + (size_t)c * 64) * 512);
    int tid = threadIdx.x;
    int d4 = tid & 127, half = tid >> 7;
    f32x4 s = {0.f, 0.f, 0.f, 0.f};
    for (int t = half; t < 64; t += 2) {
      // non-temporal: stream o without polluting L2/L3 (qkv reuses X/Wt there)
      f32x4 v = __builtin_nontemporal_load(base + (size_t)t * 128 + d4);
      s += v;
    }
    f32x4* dst = (f32x4*)(args.part + (((size_t)b * 16 + c) * 2 + half) * 512) + d4;
    __builtin_nontemporal_store(s, dst);
    return;
  }

  int qid = blk * 192 + off;            // 0..1535
  int mi = qid >= 768 ? 1 : 0; qid -= mi * 768;
  int by = qid & 63, bx = (qid >> 6) & 3, bz = qid >> 8;   // XCD-affine
  int K = mi ? 128 : 2048;
  int nt = K >> 5;
  const unsigned short* A = args.A[mi];
  int wi = mi * 3 + bz;
  const unsigned short* Bt = args.Wt[wi];
  const float* bias = args.bias[wi];

  int tid = threadIdx.x;
  int l = tid & 63, w = tid >> 6;
  int row0 = by * 128, col0 = bx * 128;
  int wrow = (w & 1) * 64, wcol = (w >> 1) * 64;
  int kg = l >> 4, lr = l & 15;

  float bv[4];
#pragma unroll
  for (int n = 0; n < 4; ++n) bv[n] = bias[col0 + wcol + n * 16 + lr];
  asm volatile("" :: "v"(bv[0]), "v"(bv[1]), "v"(bv[2]), "v"(bv[3]));

  auto stage_pair = [&](char* dbuf, int k0s) {
#pragma unroll
    for (int i = 0; i < 2; ++i) {
      int c = w * 128 + i * 64 + l;
      int B_ = c << 4;
      int e6 = ((B_ >> 6) ^ (B_ >> 8)) & 1;
      int E  = B_ ^ (e6 << 4) ^ (((B_ >> 7) & 1) << 5) ^ (((B_ >> 8) & 1) << 6);
      int r = E >> 6, s = ((E >> 4) & 3) << 3;
      stage16(A + (size_t)(row0 + r) * K + k0s + s, dbuf + (w * 128 + i * 64) * 16);
      stage16(Bt + (size_t)(col0 + r) * K + k0s + s, dbuf + 8192 + (w * 128 + i * 64) * 16);
    }
  };

  f32x4 acc[4][4] = {};
  int xorA = (lr & 7) << 4;

  stage_pair(smem, 0);
  int cur = 0;
  for (int t = 0; t < nt; ++t) {
    if (t + 1 < nt) {
      stage_pair(smem + ((cur ^ 1) << 14), (t + 1) << 5);
      asm volatile("s_waitcnt vmcnt(4)" ::: "memory");
    } else {
      asm volatile("s_waitcnt vmcnt(0)" ::: "memory");
    }
    __builtin_amdgcn_s_barrier();
    __builtin_amdgcn_sched_barrier(0);

    const char* Ab = smem + (cur << 14);
    const char* Bb = Ab + 8192;
    bf16x8 af[4], bfr[4];
#pragma unroll
    for (int m = 0; m < 4; ++m) {
      int ra = wrow + m * 16 + lr;
      int rb = wcol + m * 16 + lr;
      af[m]  = *(const bf16x8*)(Ab + (((ra << 6) + (kg << 4)) ^ xorA));
      bfr[m] = *(const bf16x8*)(Bb + (((rb << 6) + (kg << 4)) ^ xorA));
    }
#pragma unroll
    for (int m = 0; m < 4; ++m)
#pragma unroll
      for (int n = 0; n < 4; ++n)
        acc[m][n] = __builtin_amdgcn_mfma_f32_16x16x32_bf16(af[m], bfr[n], acc[m][n], 0, 0, 0);

    __builtin_amdgcn_sched_barrier(0);
    __builtin_amdgcn_s_barrier();
    cur ^= 1;
  }

  float* cst = (float*)(smem) + w * 1024;
  unsigned short* C = args.out[wi];
  int rr = l >> 3, q = l & 7;
#pragma unroll
  for (int m = 0; m < 4; ++m) {
#pragma unroll
    for (int n = 0; n < 4; ++n) {
      int g0 = (n * 16 + lr) >> 3, o0 = lr & 7;
#pragma unroll
      for (int j = 0; j < 4; ++j) {
        int row = kg * 4 + j;
        cst[row * 64 + (((g0 ^ (row & 7)) << 3) | o0)] = acc[m][n][j] + bv[n];
      }
    }
#pragma unroll
    for (int p = 0; p < 2; ++p) {
      int row = rr + p * 8;
      int grp = q ^ (row & 7);
      float4 x0 = *(const float4*)&cst[row * 64 + grp * 8];
      float4 x1 = *(const float4*)&cst[row * 64 + grp * 8 + 4];
      uint4 pk;
      pk.x = pack2(x0.x, x0.y); pk.y = pack2(x0.z, x0.w);
      pk.z = pack2(x1.x, x1.y); pk.w = pack2(x1.z, x1.w);
      *(uint4*)&C[(size_t)(row0 + wrow + m * 16 + row) * 512 + col0 + wcol + q * 8] = pk;
    }
  }
}

// ---- 3: finalize mean ------------------------------------------------------
__global__ __launch_bounds__(512) void finalize_mean_k(const float* __restrict__ part,
                                                       float* __restrict__ om) {
  int b = blockIdx.x, d = threadIdx.x;
  float s = 0.f;
  for (int c = 0; c < 32; ++c) s += part[((size_t)b * 32 + c) * 512 + d];
  om[(size_t)b * 512 + d] = s * (1.f / 1024.f);
}

// ---- 4: f32 GEMM (expand only) ---------------------------------------------
__global__ __launch_bounds__(256) void gemm_f32_k(
    const float* __restrict__ A, int lda,
    const float* __restrict__ W, int ldw,
    const float* __restrict__ bias,
    float* __restrict__ C, int ldc, int K) {
  __shared__ float As[16][65];
  __shared__ float Ws[16][64];
  int tid = threadIdx.x;
  int tx = tid & 15, ty = tid >> 4;
  int row0 = blockIdx.y * 64, col0 = blockIdx.x * 64;
  float acc[4][4] = {};
  int ar = tid >> 2, ac = (tid & 3) << 2;
  int wr = tid >> 4, wc = (tid & 15) << 2;
  for (int k0 = 0; k0 < K; k0 += 16) {
    float4 av = *(const float4*)(A + (size_t)(row0 + ar) * lda + k0 + ac);
    As[ac + 0][ar] = av.x; As[ac + 1][ar] = av.y;
    As[ac + 2][ar] = av.z; As[ac + 3][ar] = av.w;
    float4 wv = *(const float4*)(W + (size_t)(k0 + wr) * ldw + col0 + wc);
    *(float4*)&Ws[wr][wc] = wv;
    __syncthreads();
#pragma unroll
    for (int k = 0; k < 16; ++k) {
      float a0 = As[k][(ty << 2) + 0], a1 = As[k][(ty << 2) + 1];
      float a2 = As[k][(ty << 2) + 2], a3 = As[k][(ty << 2) + 3];
      float4 w = *(const float4*)&Ws[k][tx << 2];
      acc[0][0] += a0 * w.x; acc[0][1] += a0 * w.y; acc[0][2] += a0 * w.z; acc[0][3] += a0 * w.w;
      acc[1][0] += a1 * w.x; acc[1][1] += a1 * w.y; acc[1][2] += a1 * w.z; acc[1][3] += a1 * w.w;
      acc[2][0] += a2 * w.x; acc[2][1] += a2 * w.y; acc[2][2] += a2 * w.z; acc[2][3] += a2 * w.w;
      acc[3][0] += a3 * w.x; acc[3][1] += a3 * w.y; acc[3][2] += a3 * w.z; acc[3][3] += a3 * w.w;
    }
    __syncthreads();
  }
  float4 bv = *(const float4*)(bias + col0 + (tx << 2));
#pragma unroll
  for (int i = 0; i < 4; ++i) {
    float4 ov;
    ov.x = acc[i][0] + bv.x; ov.y = acc[i][1] + bv.y;
    ov.z = acc[i][2] + bv.z; ov.w = acc[i][3] + bv.w;
    *(float4*)(C + (size_t)(row0 + (ty << 2) + i) * ldc + col0 + (tx << 2)) = ov;
  }
}

// ---- dual-weight f32 GEMM ---------------------------------------------------
__global__ __launch_bounds__(256) void gemm_f32_2w_k(
    const float* __restrict__ A,
    const float* __restrict__ W0, const float* __restrict__ W1,
    const float* __restrict__ b0, const float* __restrict__ b1,
    float* __restrict__ C) {
  const float* W = (blockIdx.y >= 2) ? W1 : W0;
  const float* bias = (blockIdx.y >= 2) ? b1 : b0;
  __shared__ float As[16][65];
  __shared__ float Ws[16][64];
  int tid = threadIdx.x;
  int tx = tid & 15, ty = tid >> 4;
  int row0 = blockIdx.y * 64, col0 = blockIdx.x * 64;
  float acc[4][4] = {};
  int ar = tid >> 2, ac = (tid & 3) << 2;
  int wr = tid >> 4, wc = (tid & 15) << 2;
  for (int k0 = 0; k0 < 512; k0 += 16) {
    float4 av = *(const float4*)(A + (size_t)(row0 + ar) * 512 + k0 + ac);
    As[ac + 0][ar] = av.x; As[ac + 1][ar] = av.y;
    As[ac + 2][ar] = av.z; As[ac + 3][ar] = av.w;
    float4 wv = *(const float4*)(W + (size_t)(k0 + wr) * 512 + col0 + wc);
    *(float4*)&Ws[wr][wc] = wv;
    __syncthreads();
#pragma unroll
    for (int k = 0; k < 16; ++k) {
      float a0 = As[k][(ty << 2) + 0], a1 = As[k][(ty << 2) + 1];
      float a2 = As[k][(ty << 2) + 2], a3 = As[k][(ty << 2) + 3];
      float4 w = *(const float4*)&Ws[k][tx << 2];
      acc[0][0] += a0 * w.x; acc[0][1] += a0 * w.y; acc[0][2] += a0 * w.z; acc[0][3] += a0 * w.w;
      acc[1][0] += a1 * w.x; acc[1][1] += a1 * w.y; acc[1][2] += a1 * w.z; acc[1][3] += a1 * w.w;
      acc[2][0] += a2 * w.x; acc[2][1] += a2 * w.y; acc[2][2] += a2 * w.z; acc[2][3] += a2 * w.w;
      acc[3][0] += a3 * w.x; acc[3][1] += a3 * w.y; acc[3][2] += a3 * w.z; acc[3][3] += a3 * w.w;
    }
    __syncthreads();
  }
  float4 bv = *(const float4*)(bias + col0 + (tx << 2));
#pragma unroll
  for (int i = 0; i < 4; ++i) {
    float4 ov;
    ov.x = acc[i][0] + bv.x; ov.y = acc[i][1] + bv.y;
    ov.z = acc[i][2] + bv.z; ov.w = acc[i][3] + bv.w;
    *(float4*)(C + (size_t)(row0 + (ty << 2) + i) * 512 + col0 + (tx << 2)) = ov;
  }
}

// ---- 5: attention pool; block=(b,m), wave=head; bf16 V ---------------------
__global__ __launch_bounds__(256) void attn_pool_k(
    const unsigned short* __restrict__ qbf,
    const unsigned short* __restrict__ kbf,
    const unsigned short* __restrict__ vbf,
    float* __restrict__ pooled) {
  __shared__ float wlds[4][64];
  int b = blockIdx.x, m = blockIdx.y;
  int tid = threadIdx.x;
  int w = tid >> 6, l = tid & 63, lr = l & 15, g = l >> 4;
  size_t base = ((size_t)m * 8192 + (size_t)b * 64) * 512 + w * 128;  // head = w

  bf16x8 qf[4][4];
#pragma unroll
  for (int tb = 0; tb < 4; ++tb)
#pragma unroll
    for (int ks = 0; ks < 4; ++ks)
      qf[tb][ks] = *(const bf16x8*)(qbf + base + (size_t)(tb * 16 + lr) * 512 + ks * 32 + g * 8);

  f32x4 acc[4][4] = {};
#pragma unroll
  for (int sb = 0; sb < 4; ++sb) {
    bf16x8 kf[4];
#pragma unroll
    for (int ks = 0; ks < 4; ++ks)
      kf[ks] = *(const bf16x8*)(kbf + base + (size_t)(sb * 16 + lr) * 512 + ks * 32 + g * 8);
#pragma unroll
    for (int tb = 0; tb < 4; ++tb)
#pragma unroll
      for (int ks = 0; ks < 4; ++ks)
        acc[sb][tb] = __builtin_amdgcn_mfma_f32_16x16x32_bf16(kf[ks], qf[tb][ks], acc[sb][tb], 0, 0, 0);
  }

  const float scale = 0.08838834764831845f;
  float mx[4] = {-INFINITY, -INFINITY, -INFINITY, -INFINITY};
#pragma unroll
  for (int sb = 0; sb < 4; ++sb)
#pragma unroll
    for (int tb = 0; tb < 4; ++tb)
#pragma unroll
      for (int j = 0; j < 4; ++j) {
        acc[sb][tb][j] *= scale;
        mx[tb] = fmaxf(mx[tb], acc[sb][tb][j]);
      }
#pragma unroll
  for (int tb = 0; tb < 4; ++tb) {
    mx[tb] = fmaxf(mx[tb], __shfl_xor(mx[tb], 16));
    mx[tb] = fmaxf(mx[tb], __shfl_xor(mx[tb], 32));
  }
  float sm[4] = {0.f, 0.f, 0.f, 0.f};
#pragma unroll
  for (int sb = 0; sb < 4; ++sb)
#pragma unroll
    for (int tb = 0; tb < 4; ++tb)
#pragma unroll
      for (int j = 0; j < 4; ++j) {
        float e = expf(acc[sb][tb][j] - mx[tb]);
        acc[sb][tb][j] = e;
        sm[tb] += e;
      }
  float inv[4];
#pragma unroll
  for (int tb = 0; tb < 4; ++tb) {
    sm[tb] += __shfl_xor(sm[tb], 16);
    sm[tb] += __shfl_xor(sm[tb], 32);
    inv[tb] = 1.f / sm[tb];
  }
#pragma unroll
  for (int sb = 0; sb < 4; ++sb)
#pragma unroll
    for (int j = 0; j < 4; ++j) {
      float cs = acc[sb][0][j] * inv[0] + acc[sb][1][j] * inv[1]
               + acc[sb][2][j] * inv[2] + acc[sb][3][j] * inv[3];
      cs += __shfl_xor(cs, 1);
      cs += __shfl_xor(cs, 2);
      cs += __shfl_xor(cs, 4);
      cs += __shfl_xor(cs, 8);
      if (lr == 0) wlds[w][sb * 16 + g * 4 + j] = cs * (1.f / 64.f);
    }
  __syncthreads();

  int h = tid >> 6, c2 = (tid & 63) << 1;
  size_t vbase = ((size_t)m * 8192 + (size_t)b * 64) * 512 + h * 128 + c2;
  float s0 = 0.f, s1 = 0.f;
#pragma unroll 8
  for (int s = 0; s < 64; ++s) {
    unsigned u = *(const unsigned*)(vbf + vbase + (size_t)s * 512);
    float vlo = __builtin_bit_cast(float, u << 16);
    float vhi = __builtin_bit_cast(float, u & 0xffff0000u);
    float wv = wlds[h][s];
    s0 += wv * vlo; s1 += wv * vhi;
  }
  float2 o2 = {s0, s1};
  *(float2*)(pooled + ((size_t)m * 128 + b) * 512 + h * 128 + c2) = o2;
}

// ---- 8: G = normalize_rows(oo_raw) @ feat^T --------------------------------
__global__ __launch_bounds__(256) void ntg_k(const float* __restrict__ oo,
                                             const float* __restrict__ feat,
                                             float* __restrict__ G) {
  __shared__ float As[16][33], Bs[16][33];
  __shared__ float inv32[32];
  int tid = threadIdx.x;
  int row0 = blockIdx.y * 32, col0 = blockIdx.x * 32;
  int ar = tid >> 3, aq = tid & 7;
  int ty = tid >> 4, tx = tid & 15;
  float acc[2][2] = {};
  float ssq = 0.f;
  for (int k0 = 0; k0 < 1024; k0 += 16) {
    float2 av = *(const float2*)(oo + (size_t)(row0 + ar) * 1024 + k0 + aq * 2);
    As[aq * 2 + 0][ar] = av.x;
    As[aq * 2 + 1][ar] = av.y;
    ssq += av.x * av.x + av.y * av.y;
    int kk = k0 + aq * 2;
    float2 bv = *(const float2*)(feat + (size_t)((kk >> 9) * 128 + col0 + ar) * 512 + (kk & 511));
    Bs[aq * 2 + 0][ar] = bv.x;
    Bs[aq * 2 + 1][ar] = bv.y;
    __syncthreads();
#pragma unroll
    for (int k = 0; k < 16; ++k) {
      float a0 = As[k][ty * 2], a1 = As[k][ty * 2 + 1];
      float b0 = Bs[k][tx * 2], b1 = Bs[k][tx * 2 + 1];
      acc[0][0] += a0 * b0; acc[0][1] += a0 * b1;
      acc[1][0] += a1 * b0; acc[1][1] += a1 * b1;
    }
    __syncthreads();
  }
  ssq += __shfl_xor(ssq, 1);
  ssq += __shfl_xor(ssq, 2);
  ssq += __shfl_xor(ssq, 4);
  if (aq == 0) inv32[ar] = 1.f / fmaxf(sqrtf(ssq), 1e-12f);
  __syncthreads();
#pragma unroll
  for (int i = 0; i < 2; ++i)
#pragma unroll
    for (int j = 0; j < 2; ++j)
      G[(size_t)(row0 + ty * 2 + i) * 128 + col0 + tx * 2 + j] = acc[i][j] * inv32[ty * 2 + i];
}

// ---- 9: final loss/acc ------------------------------------------------------
__global__ __launch_bounds__(128) void final_k(const float* __restrict__ G,
                                               const int* __restrict__ gmask,
                                               float* __restrict__ out) {
  __shared__ float cm[2][128], vd[2][128], tp[2][128], cv[2][128];
  __shared__ int gm[128];
  int b = threadIdx.x;
  gm[b] = gmask[b];
  __syncthreads();
  for (int r = 0; r < 2; ++r) {
    bool gb = gm[b] != 0;
    float s0 = G[b * 128 + b];
    int cnt = 0;
    float lsum = 0.f, selsum = 0.f, smax = -INFINITY;
    bool anym = false;
    for (int i = 0; i < 128; ++i) {
      int j = (b - i + 128) & 127;
      bool mk = gb && (gm[j] != 0);
      float sv = (r == 0) ? G[b * 128 + j] : G[j * 128 + b];
      if (mk) {
        selsum += sv; anym = true;
        smax = fmaxf(smax, sv);
        if (i >= 1) { cnt++; lsum += fmaxf(0.f, 1.f + sv - s0); }
      }
    }
    cm[r][b] = (cnt > 0) ? (lsum / (float)cnt) : 0.f;
    vd[r][b] = (cnt > 0) ? 1.f : 0.f;
    bool colvalid = (selsum != 0.f) && anym;
    tp[r][b] = (colvalid && (s0 >= smax)) ? 1.f : 0.f;
    cv[r][b] = colvalid ? 1.f : 0.f;
  }
  __syncthreads();
  if (b == 0) {
    float loss = 0.f, acc = 0.f;
    for (int r = 0; r < 2; ++r) {
      float scm = 0, svd = 0, stp = 0, scv = 0;
      for (int i = 0; i < 128; ++i) { scm += cm[r][i]; svd += vd[r][i]; stp += tp[r][i]; scv += cv[r][i]; }
      loss += scm / fmaxf(svd, 1.f);
      acc += stp / fmaxf(scv, 1.f);
    }
    out[0] = loss;
    out[1] = acc * 0.5f;
  }
}

extern "C" void kernel_launch(void* const* d_in, const int* in_sizes, int n_in,
                              void* d_out, int out_size, void* d_ws, size_t ws_size,
                              hipStream_t stream) {
  const float* o     = (const float*)d_in[0];
  const float* rgb   = (const float*)d_in[1];
  const float* audio = (const float*)d_in[2];
  const int* gmask   = (const int*)d_in[3];
  const float* W[2][10];
  for (int m = 0; m < 2; ++m)
    for (int w = 0; w < 10; ++w) W[m][w] = (const float*)d_in[4 + m * 10 + w];
  const float* expand_W = (const float*)d_in[24];
  const float* expand_b = (const float*)d_in[25];

  char* ws = (char*)d_ws;
  float* part = (float*)(ws + B_PART);
  float* om   = (float*)(ws + B_OM);
  float* oo   = (float*)(ws + B_OO);
  float* G    = (float*)(ws + B_G);
  float* pp2  = (float*)(ws + B_PP);
  float* po2  = (float*)(ws + B_PO);
  float* feat2= (float*)(ws + B_FEAT);
  unsigned short* qbf = (unsigned short*)(ws + B_QBF);
  unsigned short* kbf = (unsigned short*)(ws + B_KBF);
  unsigned short* vbf = (unsigned short*)(ws + B_VBF);
  unsigned short* xrb = (unsigned short*)(ws + B_XR);
  unsigned short* xab = (unsigned short*)(ws + B_XA);
  unsigned short* wt  = (unsigned short*)(ws + B_WT);
  unsigned short* wtp[6];
  wtp[0] = wt;
  wtp[1] = wtp[0] + (size_t)512 * 2048;
  wtp[2] = wtp[1] + (size_t)512 * 2048;
  wtp[3] = wtp[2] + (size_t)512 * 2048;
  wtp[4] = wtp[3] + (size_t)512 * 128;
  wtp[5] = wtp[4] + (size_t)512 * 128;

  // 1: prep (casts only)
  PrepArgs pa;
  pa.xr = rgb;   pa.xrb = xrb;
  pa.xa = audio; pa.xab = xab;
  pa.w[0] = W[0][0]; pa.w[1] = W[0][2]; pa.w[2] = W[0][4];
  pa.w[3] = W[1][0]; pa.w[4] = W[1][2]; pa.w[5] = W[1][4];
  for (int i = 0; i < 6; ++i) pa.wt[i] = wtp[i];
  prep_k<<<1904, 256, 0, stream>>>(pa);

  // 2: qkv + interleaved mean partials (NT o-read)
  QkvAll qa;
  qa.A[0] = xrb; qa.A[1] = xab;
  for (int i = 0; i < 6; ++i) qa.Wt[i] = wtp[i];
  qa.bias[0] = W[0][1]; qa.bias[1] = W[0][3]; qa.bias[2] = W[0][5];
  qa.bias[3] = W[1][1]; qa.bias[4] = W[1][3]; qa.bias[5] = W[1][5];
  qa.out[0] = qbf;                       qa.out[1] = kbf;                       qa.out[2] = vbf;
  qa.out[3] = qbf + (size_t)8192 * 512;  qa.out[4] = kbf + (size_t)8192 * 512;  qa.out[5] = vbf + (size_t)8192 * 512;
  qa.o = o; qa.part = part;
  qkv_mean_k<<<3584, 256, 0, stream>>>(qa);

  // 3-4: oo branch
  finalize_mean_k<<<128, 512, 0, stream>>>(part, om);
  gemm_f32_k<<<dim3(16, 2), 256, 0, stream>>>(om, 512, expand_W, 1024, expand_b, oo, 1024, 512);

  // 5: attention pools
  attn_pool_k<<<dim3(128, 2), 256, 0, stream>>>(qbf, kbf, vbf, pp2);

  // 6-7: po = pp @ Wo + bo ; feat = po @ W2 + b2
  gemm_f32_2w_k<<<dim3(8, 4), 256, 0, stream>>>(pp2, W[0][6], W[1][6], W[0][7], W[1][7], po2);
  gemm_f32_2w_k<<<dim3(8, 4), 256, 0, stream>>>(po2, W[0][8], W[1][8], W[0][9], W[1][9], feat2);

  // 8-9: ranking
  ntg_k<<<dim3(4, 4), 256, 0, stream>>>(oo, feat2, G);
  final_k<<<1, 128, 0, stream>>>(G, gmask, (float*)d_out);
}